// Round 1
// 209.643 us; speedup vs baseline: 1.1440x; 1.1440x over previous
//
#include <hip/hip_runtime.h>
#include <math.h>

// CapsuleLayer dynamic routing — round 8: MFMA rewrite.
// B=64, N=4096, I=8, C=32, D=16, 3 routing iterations.
//
// Round-7 post-mortem: fused_pass was VALU/latency-bound (MfmaUtil 0,
// VALUBusy 60%, HBM 8.8%). hat[b,c,n,j] per n is a [512x8]@[8x64] GEMM with
// K=8 == v_mfma_f32_32x32x8_f16. This version computes hat on matrix cores.
//
// fused_pass: grid 256 = 2 b-tiles x 128 n-blocks (bt-pair co-XCD), block =
// 8 waves x 512thr. Wave w owns m-tiles {2w,2w+1} (c = 4w..4w+3) x 32 b,
// loops 32 n. MFMA D layout: col(b)=lane&31, row=(reg&3)+8*(reg>>2)+4*hi.
// Softmax over c: in-lane 4-c partial + shfl_xor(32) + cross-wave pd[] LDS
// reduce (1 barrier/n, double-buffered). Pass1 (uniform c=1/32) accumulates
// in MFMA C (no softmax) and converts W f32->fp16 into Wh (bt==0 stores) —
// no separate convert kernel. x read f32 + cvt in-reg every pass.
//
// ws: Wh fp16 [n][cj][i] 32 MiB | partial u32(h2) [bid][bl][cjp] 8 MiB |
//     OcumG fp16 [b][cj] 64 KiB  (40.07 MiB total)

typedef __fp16 h2 __attribute__((ext_vector_type(2)));
typedef __fp16 half4 __attribute__((ext_vector_type(4)));
typedef float f32x16 __attribute__((ext_vector_type(16)));

union U2 { h2 h; unsigned u; };

__device__ __forceinline__ float fdot2(h2 a, h2 b, float c) {
    return __builtin_amdgcn_fdot2(a, b, c, false);
}
__device__ __forceinline__ h2 uash2(unsigned u) { U2 t; t.u = u; return t.h; }

template <int PASS0>
__global__ __launch_bounds__(512, 2) void fused_pass(
    const float* __restrict__ W,      // [C][N][D][I] f32
    const float* __restrict__ x,      // [B][N][I] f32
    ushort* __restrict__ Wh,          // [N][CJ][I] fp16
    const ushort* __restrict__ OcumG, // [B][CJ] fp16
    unsigned* __restrict__ partial)   // [bid][bl 32][cjp 256] u32(h2)
{
    const int bid = blockIdx.x;
    const int bt = bid >> 7, nblk = bid & 127;
    const int n0 = nblk * 32;
    const int t = threadIdx.x, l = t & 63, w = t >> 6;
    const int bl = l & 31, hi = l >> 5;
    const int b = bt * 32 + bl;

    __shared__ __align__(16) float pd[2][32][12];  // [buf][b][wave] e-partials
    __shared__ unsigned sep[8192];                 // 32KB epilogue staging

    const int cj0 = w * 64 + bl, cj1 = cj0 + 32;
    const float* xb = x + (size_t)b * 32768 + (size_t)n0 * 8 + hi * 4;
    const float* wb0 = W + (size_t)(cj0 >> 4) * 524288 + (size_t)n0 * 128 + (cj0 & 15) * 8 + hi * 4;
    const float* wb1 = W + (size_t)(cj1 >> 4) * 524288 + (size_t)n0 * 128 + (cj1 & 15) * 8 + hi * 4;
    ushort* whp0 = Wh + ((size_t)n0 * 512 + cj0) * 8 + hi * 4;
    ushort* whp1 = Wh + ((size_t)n0 * 512 + cj1) * 8 + hi * 4;

    h2 oc[2][8];
    if (!PASS0) {
        const unsigned* og = reinterpret_cast<const unsigned*>(OcumG);
        #pragma unroll
        for (int mt = 0; mt < 2; ++mt) {
            const int cA = 4 * w + 2 * mt;
            const unsigned idx = (unsigned)b * 256 + cA * 8 + hi * 2;
            oc[mt][0] = uash2(og[idx]);      oc[mt][1] = uash2(og[idx + 1]);
            oc[mt][2] = uash2(og[idx + 4]);  oc[mt][3] = uash2(og[idx + 5]);
            oc[mt][4] = uash2(og[idx + 8]);  oc[mt][5] = uash2(og[idx + 9]);
            oc[mt][6] = uash2(og[idx + 12]); oc[mt][7] = uash2(og[idx + 13]);
        }
    }

    f32x16 zero = {};
    f32x16 acc0 = {}, acc1 = {};

    if (PASS0) {
        float4 wv0 = *reinterpret_cast<const float4*>(wb0);
        float4 wv1 = *reinterpret_cast<const float4*>(wb1);
        float4 xv  = *reinterpret_cast<const float4*>(xb);
        #pragma unroll 1
        for (int s = 0; s < 32; ++s) {
            float4 wv0n, wv1n, xvn;
            if (s < 31) {
                wv0n = *reinterpret_cast<const float4*>(wb0 + (s + 1) * 128);
                wv1n = *reinterpret_cast<const float4*>(wb1 + (s + 1) * 128);
                xvn  = *reinterpret_cast<const float4*>(xb + (s + 1) * 8);
            }
            half4 a0, a1, bf;
            a0[0] = (__fp16)wv0.x; a0[1] = (__fp16)wv0.y; a0[2] = (__fp16)wv0.z; a0[3] = (__fp16)wv0.w;
            a1[0] = (__fp16)wv1.x; a1[1] = (__fp16)wv1.y; a1[2] = (__fp16)wv1.z; a1[3] = (__fp16)wv1.w;
            bf[0] = (__fp16)xv.x;  bf[1] = (__fp16)xv.y;  bf[2] = (__fp16)xv.z;  bf[3] = (__fp16)xv.w;
            if (bt == 0) {  // fold W conversion into pass 1
                *reinterpret_cast<half4*>(whp0 + (size_t)s * 4096) = a0;
                *reinterpret_cast<half4*>(whp1 + (size_t)s * 4096) = a1;
            }
            acc0 = __builtin_amdgcn_mfma_f32_32x32x8f16(a0, bf, acc0, 0, 0, 0);
            acc1 = __builtin_amdgcn_mfma_f32_32x32x8f16(a1, bf, acc1, 0, 0, 0);
            wv0 = wv0n; wv1 = wv1n; xv = xvn;
        }
        #pragma unroll
        for (int r = 0; r < 16; ++r) { acc0[r] *= 0.03125f; acc1[r] *= 0.03125f; }
    } else {
        half4 a0 = *reinterpret_cast<const half4*>(whp0);
        half4 a1 = *reinterpret_cast<const half4*>(whp1);
        float4 xv = *reinterpret_cast<const float4*>(xb);
        #pragma unroll 1
        for (int s = 0; s < 32; ++s) {
            half4 a0n, a1n; float4 xvn;
            if (s < 31) {
                a0n = *reinterpret_cast<const half4*>(whp0 + (size_t)(s + 1) * 4096);
                a1n = *reinterpret_cast<const half4*>(whp1 + (size_t)(s + 1) * 4096);
                xvn = *reinterpret_cast<const float4*>(xb + (s + 1) * 8);
            }
            half4 bf;
            bf[0] = (__fp16)xv.x; bf[1] = (__fp16)xv.y; bf[2] = (__fp16)xv.z; bf[3] = (__fp16)xv.w;
            f32x16 d0 = __builtin_amdgcn_mfma_f32_32x32x8f16(a0, bf, zero, 0, 0, 0);
            f32x16 d1 = __builtin_amdgcn_mfma_f32_32x32x8f16(a1, bf, zero, 0, 0, 0);
            // pack hat rows (j pairs) for coupling dots
            h2 h0[8], h1[8];
            #pragma unroll
            for (int q = 0; q < 8; ++q) {
                h0[q] = __builtin_amdgcn_cvt_pkrtz(d0[2 * q], d0[2 * q + 1]);
                h1[q] = __builtin_amdgcn_cvt_pkrtz(d1[2 * q], d1[2 * q + 1]);
            }
            // logits: this half-lane's 8 j's of each c; q0..3 -> cA, q4..7 -> cB
            float pA0 = fdot2(h0[3], oc[0][3], fdot2(h0[2], oc[0][2], fdot2(h0[1], oc[0][1], fdot2(h0[0], oc[0][0], 0.f))));
            float pB0 = fdot2(h0[7], oc[0][7], fdot2(h0[6], oc[0][6], fdot2(h0[5], oc[0][5], fdot2(h0[4], oc[0][4], 0.f))));
            float pA1 = fdot2(h1[3], oc[1][3], fdot2(h1[2], oc[1][2], fdot2(h1[1], oc[1][1], fdot2(h1[0], oc[1][0], 0.f))));
            float pB1 = fdot2(h1[7], oc[1][7], fdot2(h1[6], oc[1][6], fdot2(h1[5], oc[1][5], fdot2(h1[4], oc[1][4], 0.f))));
            pA0 += __shfl_xor(pA0, 32, 64);
            pB0 += __shfl_xor(pB0, 32, 64);
            pA1 += __shfl_xor(pA1, 32, 64);
            pB1 += __shfl_xor(pB1, 32, 64);
            float eA0 = __expf(pA0), eB0 = __expf(pB0), eA1 = __expf(pA1), eB1 = __expf(pB1);
            const int buf = s & 1;
            if (l < 32) pd[buf][bl][w] = eA0 + eB0 + eA1 + eB1;  // 4-c partial
            __syncthreads();
            const float4 q0 = *reinterpret_cast<const float4*>(&pd[buf][bl][0]);
            const float4 q1 = *reinterpret_cast<const float4*>(&pd[buf][bl][4]);
            const float rd = __builtin_amdgcn_rcpf(q0.x + q0.y + q0.z + q0.w +
                                                   q1.x + q1.y + q1.z + q1.w);
            const float cA0 = eA0 * rd, cB0 = eB0 * rd, cA1 = eA1 * rd, cB1 = eB1 * rd;
            #pragma unroll
            for (int r = 0; r < 8; ++r)  { acc0[r] += d0[r] * cA0; acc1[r] += d1[r] * cA1; }
            #pragma unroll
            for (int r = 8; r < 16; ++r) { acc0[r] += d0[r] * cB0; acc1[r] += d1[r] * cB1; }
            a0 = a0n; a1 = a1n; xv = xvn;
        }
    }

    // ---- epilogue: stage h2 partial tile in LDS (XOR-swizzled), copy out --
    #pragma unroll
    for (int mt = 0; mt < 2; ++mt) {
        #pragma unroll
        for (int q = 0; q < 8; ++q) {
            const float e0 = mt ? acc1[2 * q] : acc0[2 * q];
            const float e1 = mt ? acc1[2 * q + 1] : acc0[2 * q + 1];
            U2 u; u.h = __builtin_amdgcn_cvt_pkrtz(e0, e1);
            const int cjp = w * 32 + mt * 16 + 4 * (q >> 1) + (q & 1) + 2 * hi;
            sep[bl * 256 + (cjp ^ bl)] = u.u;   // swizzle: conflict-free banks
        }
    }
    __syncthreads();
    const unsigned gbase = (unsigned)bid * 8192;
    #pragma unroll
    for (int u = 0; u < 16; ++u) {
        const int idx = t + u * 512;
        const int ubl = idx >> 8, ucjp = idx & 255;
        partial[gbase + idx] = sep[ubl * 256 + (ucjp ^ ubl)];
    }
}

// ---- final reduce + squash + Ocum update ----------------------------------

__global__ __launch_bounds__(256) void reduce_squash(const unsigned* __restrict__ partial32,
                                                     ushort* __restrict__ OcumG,
                                                     float* __restrict__ out,
                                                     int passIdx) {
    const int tid = blockIdx.x * 256 + threadIdx.x;  // 0..16383
    const int b = tid >> 8, cjp = tid & 255;
    const int bt = b >> 5, bl = b & 31;
    const unsigned base = (unsigned)bt * 1048576 + (unsigned)bl * 256 + cjp;
    float sx = 0.f, sy = 0.f;
    #pragma unroll 8
    for (int nb = 0; nb < 128; ++nb) {
        U2 v; v.u = partial32[base + nb * 8192];
        sx += (float)v.h.x;
        sy += (float)v.h.y;
    }
    float s2 = sx * sx + sy * sy;                    // 16 j live in 8 lanes
    s2 += __shfl_xor(s2, 1, 64);
    s2 += __shfl_xor(s2, 2, 64);
    s2 += __shfl_xor(s2, 4, 64);
    float scale = (s2 / (1.f + s2)) / sqrtf(s2 + 1e-7f);
    float o0 = scale * sx, o1 = scale * sy;

    unsigned* ocp = reinterpret_cast<unsigned*>(OcumG) + b * 256 + cjp;
    float a0 = o0, a1 = o1;
    if (passIdx) {
        U2 old; old.u = *ocp;
        a0 += (float)old.h.x;
        a1 += (float)old.h.y;
    }
    U2 nw; nw.h = __builtin_amdgcn_cvt_pkrtz(a0, a1);
    *ocp = nw.u;

    if (passIdx == 2) {
        out[b * 512 + cjp * 2] = o0;
        out[b * 512 + cjp * 2 + 1] = o1;
    }
}

// ---- host ------------------------------------------------------------------

extern "C" void kernel_launch(void* const* d_in, const int* in_sizes, int n_in,
                              void* d_out, int out_size, void* d_ws, size_t ws_size,
                              hipStream_t stream) {
    const float* x = (const float*)d_in[0];
    const float* W = (const float*)d_in[1];
    float* out = (float*)d_out;

    char* ws = (char*)d_ws;
    ushort* Wh = (ushort*)ws;                                       // 32 MiB
    unsigned* partialU = (unsigned*)(ws + (size_t)32 * 1024 * 1024); // 8 MiB
    ushort* OcumG = (ushort*)(ws + (size_t)40 * 1024 * 1024);        // 64 KiB

    fused_pass<1><<<256, 512, 0, stream>>>(W, x, Wh, OcumG, partialU);
    reduce_squash<<<64, 256, 0, stream>>>(partialU, OcumG, out, 0);
    fused_pass<0><<<256, 512, 0, stream>>>(W, x, Wh, OcumG, partialU);
    reduce_squash<<<64, 256, 0, stream>>>(partialU, OcumG, out, 1);
    fused_pass<0><<<256, 512, 0, stream>>>(W, x, Wh, OcumG, partialU);
    reduce_squash<<<64, 256, 0, stream>>>(partialU, OcumG, out, 2);
}